// Round 18
// baseline (76.125 us; speedup 1.0000x reference)
//
#include <hip/hip_runtime.h>

#define S 2048
#define B 2
#define H 1024
#define NH 16
#define HD 64
#define THREE_H 3072
#define ROWS (S*B)   // 4096

typedef __attribute__((ext_vector_type(8))) short short8;
typedef __attribute__((ext_vector_type(4))) float f32x4;
typedef const __attribute__((address_space(1))) unsigned int* gptr_t;
typedef __attribute__((address_space(3))) unsigned int* lptr_t;

#define N8_A (ROWS * H / 8)        // 524288
#define N8_W (THREE_H * H / 8)     // 393216

__device__ __forceinline__ ushort f2bf(float f) {
    union { float f; unsigned u; } v; v.f = f;
    unsigned r = v.u + 0x7fffu + ((v.u >> 16) & 1u);
    return (ushort)(r >> 16);
}
__device__ __forceinline__ float bf2f(ushort u) {
    union { unsigned u; float f; } v; v.u = ((unsigned)u) << 16;
    return v.f;
}

// ---------------------------------------------------------------------------
// Cast f32 -> bf16 for A and W in one launch (R12-proven)
// ---------------------------------------------------------------------------
__global__ void cast_both(const float* __restrict__ A, const float* __restrict__ W,
                          ushort* __restrict__ Ab, ushort* __restrict__ Wb) {
    int i = blockIdx.x * 256 + threadIdx.x;
    const float4* s4;
    ushort* dst;
    if (i < N8_A) { s4 = (const float4*)A; dst = Ab; }
    else if (i < N8_A + N8_W) { s4 = (const float4*)W; dst = Wb; i -= N8_A; }
    else return;
    float4 a = s4[2 * i], b = s4[2 * i + 1];
    short8 o;
    o[0] = f2bf(a.x); o[1] = f2bf(a.y); o[2] = f2bf(a.z); o[3] = f2bf(a.w);
    o[4] = f2bf(b.x); o[5] = f2bf(b.y); o[6] = f2bf(b.z); o[7] = f2bf(b.w);
    *(short8*)(dst + 8 * (size_t)i) = o;
}

// ---------------------------------------------------------------------------
// K1: bf16 MFMA GEMM (R12-proven best). 128x128 tile, 8 waves (4x2), BK=32,
// double-buffered 32 KB LDS, STAGE-next-then-compute, conflict-free XOR
// swizzle (bits 1-2 of row; verified 0 conflicts). Epilogue: Q -> [bh][s][d];
// K,V -> [bh][d][t] packed-uint direct transposed stores.
// ---------------------------------------------------------------------------
__global__ __launch_bounds__(512) void qkv_gemm_mfma(const ushort* __restrict__ Abf,
                                                     const ushort* __restrict__ Wbf,
                                                     const float* __restrict__ bias,
                                                     ushort* __restrict__ Qb,
                                                     ushort* __restrict__ Ktd,
                                                     ushort* __restrict__ Vtd) {
    __shared__ ushort Abuf[2][128 * 32];   // 16 KB
    __shared__ ushort Bbuf[2][128 * 32];   // 16 KB
    const int tid = threadIdx.x;
    const int wave = tid >> 6, lane = tid & 63;
    const int wr = wave >> 1, wc = wave & 1;     // 4x2 wave grid
    const int row0 = blockIdx.x * 128;
    const int col0 = blockIdx.y * 128;

    f32x4 acc[2][4] = {};

    const int lrow = lane >> 2;                             // 0..15 row in 16-row chunk
    const int gk = ((lane & 3) ^ ((lrow >> 1) & 3)) * 8;    // inverse-swizzled src octet
    const int il = lane & 15, ko = lane >> 4;

    const size_t arow = (size_t)(row0 + wave * 16 + lrow) * H + gk;
    const size_t wrow = (size_t)(col0 + wave * 16 + lrow) * H + gk;
    const int ldst = wave * 512 + lane * 8;

#define STAGE(buf, k0)                                                      \
    {                                                                       \
        __builtin_amdgcn_global_load_lds((gptr_t)&Abf[arow + (k0)],         \
            (lptr_t)&Abuf[buf][ldst], 16, 0, 0);                            \
        __builtin_amdgcn_global_load_lds((gptr_t)&Wbf[wrow + (k0)],         \
            (lptr_t)&Bbuf[buf][ldst], 16, 0, 0);                            \
    }

#define COMPUTE(buf)                                                        \
    {                                                                       \
        short8 af[2], bfr[4];                                               \
        _Pragma("unroll")                                                   \
        for (int m = 0; m < 2; ++m) {                                       \
            int ar = wr * 32 + m * 16 + il;                                 \
            af[m] = *(const short8*)&Abuf[buf][ar * 32 + (ko ^ ((ar >> 1) & 3)) * 8]; \
        }                                                                   \
        _Pragma("unroll")                                                   \
        for (int n = 0; n < 4; ++n) {                                       \
            int br = wc * 64 + n * 16 + il;                                 \
            bfr[n] = *(const short8*)&Bbuf[buf][br * 32 + (ko ^ ((br >> 1) & 3)) * 8]; \
        }                                                                   \
        _Pragma("unroll")                                                   \
        for (int m = 0; m < 2; ++m)                                         \
            _Pragma("unroll")                                               \
            for (int n = 0; n < 4; ++n)                                     \
                acc[m][n] = __builtin_amdgcn_mfma_f32_16x16x32_bf16(af[m], bfr[n], acc[m][n], 0, 0, 0); \
    }

    // prologue: stage tile 0, drain, enter steady state
    STAGE(0, 0);
    __syncthreads();
    int cur = 0;
    for (int t = 0; t < 31; ++t) {
        STAGE(cur ^ 1, (t + 1) * 32);   // issue next tile (stays in flight over compute)
        COMPUTE(cur);
        __syncthreads();                 // drains vmcnt: next tile ready; buf[cur] free
        cur ^= 1;
    }
    COMPUTE(cur);                        // last tile, no further staging
#undef STAGE
#undef COMPUTE

    // ---- epilogue (proven scatter; wave rows = wr*32 + m*16) ----
#pragma unroll
    for (int n = 0; n < 4; ++n) {
        int cbase = col0 + wc * 64 + n * 16;     // within one 64-col (h,sel) segment
        int h   = cbase / 192;
        int r3  = cbase % 192;
        int sel = r3 >> 6;                       // 0=q 1=k 2=v, wave-uniform
        int d   = (r3 & 63) + il;
        float bv = bias[cbase + il];
        if (sel == 0) {
#pragma unroll
            for (int m = 0; m < 2; ++m) {
                int rowb = row0 + wr * 32 + m * 16 + ko * 4;
#pragma unroll
                for (int j = 0; j < 4; ++j) {
                    int r = rowb + j;
                    int s = r >> 1, b = r & 1;   // r = s*B + b, B=2
                    Qb[((size_t)((b * NH + h) * S + s)) * HD + d] = f2bf(acc[m][n][j] + bv);
                }
            }
        } else {
            ushort* dst = (sel == 1) ? Ktd : Vtd;
            const size_t ro0 = ((size_t)(h)      * HD + d) * S;   // b=0 row
            const size_t ro1 = ((size_t)(NH + h) * HD + d) * S;   // b=1 row
#pragma unroll
            for (int m = 0; m < 2; ++m) {
                int t0 = (row0 + wr * 32 + m * 16 + ko * 4) >> 1;  // even
                uint lo = (uint)f2bf(acc[m][n][0] + bv) |
                          ((uint)f2bf(acc[m][n][2] + bv) << 16);   // t0,t0+1 (b=0)
                uint hi = (uint)f2bf(acc[m][n][1] + bv) |
                          ((uint)f2bf(acc[m][n][3] + bv) << 16);   // t0,t0+1 (b=1)
                *(uint*)&dst[ro0 + t0] = lo;
                *(uint*)&dst[ro1 + t0] = hi;
            }
        }
    }
}

// ---------------------------------------------------------------------------
// V suffix-scan, one wave per (bh,d) row of 2048 t, in place on Vtd. (R12)
// ---------------------------------------------------------------------------
__global__ __launch_bounds__(256) void vscan(ushort* __restrict__ Vtd) {
    const int row = blockIdx.x * 4 + (threadIdx.x >> 6);  // 0..2047 = bh*64+d
    const int lane = threadIdx.x & 63;
    ushort* vp = Vtd + (size_t)row * S + lane * 32;
    float v[32];
#pragma unroll
    for (int q = 0; q < 4; ++q) {
        short8 x = *(const short8*)(vp + q * 8);
#pragma unroll
        for (int k = 0; k < 8; ++k) v[q * 8 + k] = bf2f((ushort)x[k]);
    }
    float sum = 0.f;
#pragma unroll
    for (int k = 0; k < 32; ++k) sum += v[k];
    float t = sum;
#pragma unroll
    for (int off = 1; off < 64; off <<= 1) {
        float o = __shfl_down(t, off, 64);
        if (lane + off < 64) t += o;
    }
    float acc = t - sum;   // exclusive suffix (sum of lanes > lane)
#pragma unroll
    for (int k = 31; k >= 0; --k) { acc += v[k]; v[k] = acc; }
#pragma unroll
    for (int q = 0; q < 4; ++q) {
        short8 o;
#pragma unroll
        for (int k = 0; k < 8; ++k) o[k] = f2bf(v[q * 8 + k]);
        *(short8*)(vp + q * 8) = o;
    }
}

// ---------------------------------------------------------------------------
// K3: M[i][j] = sum_t Ktd[i][t]*Vtd[j][t] via MFMA; cross-wave LDS reduce
// -> Mpart has 4 slices. (R12-proven)
// ---------------------------------------------------------------------------
__global__ __launch_bounds__(256) void kvm_mfma(const ushort* __restrict__ Kt,
                                                const ushort* __restrict__ Vt,
                                                float* __restrict__ Mpart) {
    __shared__ float red[2][4096];   // 32 KB
    const int bh = blockIdx.x, kb = blockIdx.y;
    const int tid = threadIdx.x, wave = tid >> 6, lane = tid & 63;
    const int slice = kb * 4 + wave;
    const ushort* Kp = Kt + (size_t)bh * HD * S;
    const ushort* Vp = Vt + (size_t)bh * HD * S;
    f32x4 acc[4][4] = {};
    const int il = lane & 15, g = lane >> 4;
    const int tbase = slice * 128 + g * 8;
#pragma unroll
    for (int ks = 0; ks < 4; ++ks) {
        const int t = tbase + ks * 32;
        short8 af[4], bfv[4];
#pragma unroll
        for (int m = 0; m < 4; ++m) af[m]  = *(const short8*)&Kp[(size_t)(m * 16 + il) * S + t];
#pragma unroll
        for (int n = 0; n < 4; ++n) bfv[n] = *(const short8*)&Vp[(size_t)(n * 16 + il) * S + t];
#pragma unroll
        for (int m = 0; m < 4; ++m)
#pragma unroll
            for (int n = 0; n < 4; ++n)
                acc[m][n] = __builtin_amdgcn_mfma_f32_16x16x32_bf16(af[m], bfv[n], acc[m][n], 0, 0, 0);
    }
#define DUMP(dstbuf)                                                        \
    { float* _d = (dstbuf);                                                 \
      _Pragma("unroll") for (int m = 0; m < 4; ++m)                         \
      _Pragma("unroll") for (int n = 0; n < 4; ++n)                         \
      _Pragma("unroll") for (int j = 0; j < 4; ++j)                         \
          _d[(m * 16 + g * 4 + j) * 64 + n * 16 + il] = acc[m][n][j]; }
#define ADDIN(srcbuf)                                                       \
    { const float* _s = (srcbuf);                                           \
      _Pragma("unroll") for (int m = 0; m < 4; ++m)                         \
      _Pragma("unroll") for (int n = 0; n < 4; ++n)                         \
      _Pragma("unroll") for (int j = 0; j < 4; ++j)                         \
          acc[m][n][j] += _s[(m * 16 + g * 4 + j) * 64 + n * 16 + il]; }
    if (wave == 1) DUMP(red[0]);
    if (wave == 3) DUMP(red[1]);
    __syncthreads();
    if (wave == 0) ADDIN(red[0]);
    if (wave == 2) ADDIN(red[1]);
    __syncthreads();
    if (wave == 2) DUMP(red[0]);
    __syncthreads();
    if (wave == 0) {
        ADDIN(red[0]);
        float* Mp = Mpart + ((size_t)kb * 32 + bh) * 4096;
#pragma unroll
        for (int m = 0; m < 4; ++m)
#pragma unroll
            for (int n = 0; n < 4; ++n)
#pragma unroll
                for (int j = 0; j < 4; ++j)
                    Mp[(m * 16 + g * 4 + j) * 64 + n * 16 + il] = acc[m][n][j];
    }
#undef DUMP
#undef ADDIN
}

// ---------------------------------------------------------------------------
// K4: out = scale * Q·M via MFMA; folds the 4-slice Mpart reduce. (R12)
// ---------------------------------------------------------------------------
__global__ __launch_bounds__(256) void qm_mfma(const ushort* __restrict__ Qb,
                                               const float* __restrict__ Mpart,
                                               float* __restrict__ out) {
    __shared__ ushort Mt[64][72];   // Mt[d][i] = M[i][d], bf16
    const int bh = blockIdx.x, b = bh >> 4, h = bh & 15;
    const int tid = threadIdx.x;
    {
        const int i = tid >> 2, jq = (tid & 3) * 16;
        f32x4 s0 = {}, s1 = {}, s2 = {}, s3 = {};
#pragma unroll
        for (int sl = 0; sl < 4; ++sl) {
            const float* p = Mpart + ((size_t)sl * 32 + bh) * 4096 + i * 64 + jq;
            s0 += *(const f32x4*)(p);
            s1 += *(const f32x4*)(p + 4);
            s2 += *(const f32x4*)(p + 8);
            s3 += *(const f32x4*)(p + 12);
        }
#pragma unroll
        for (int k = 0; k < 4; ++k) {
            Mt[jq + 0  + k][i] = f2bf(s0[k]);
            Mt[jq + 4  + k][i] = f2bf(s1[k]);
            Mt[jq + 8  + k][i] = f2bf(s2[k]);
            Mt[jq + 12 + k][i] = f2bf(s3[k]);
        }
    }
    __syncthreads();
    const int wave = tid >> 6, lane = tid & 63;
    const int sl15 = lane & 15, koct = (lane >> 4) * 8;
    const int s0b = blockIdx.y * 256 + wave * 64;
    f32x4 acc[4][4] = {};
#pragma unroll
    for (int ks = 0; ks < 2; ++ks) {
        short8 af[4], bfv[4];
#pragma unroll
        for (int m = 0; m < 4; ++m) {
            int s = s0b + m * 16 + sl15;
            af[m] = *(const short8*)&Qb[((size_t)bh * S + s) * HD + ks * 32 + koct];
        }
#pragma unroll
        for (int n = 0; n < 4; ++n)
            bfv[n] = *(const short8*)&Mt[n * 16 + sl15][ks * 32 + koct];
#pragma unroll
        for (int m = 0; m < 4; ++m)
#pragma unroll
            for (int n = 0; n < 4; ++n)
                acc[m][n] = __builtin_amdgcn_mfma_f32_16x16x32_bf16(af[m], bfv[n], acc[m][n], 0, 0, 0);
    }
    const float scale = 0.125f * 0.02209708691207961f;  // HD^-0.5 * S^-0.5
#pragma unroll
    for (int m = 0; m < 4; ++m)
#pragma unroll
        for (int n = 0; n < 4; ++n)
#pragma unroll
            for (int j = 0; j < 4; ++j) {
                int s = s0b + m * 16 + (lane >> 4) * 4 + j;
                int d = n * 16 + sl15;
                out[(size_t)(s * B + b) * H + h * 64 + d] = acc[m][n][j] * scale;
            }
}

// ---------------------------------------------------------------------------
extern "C" void kernel_launch(void* const* d_in, const int* in_sizes, int n_in,
                              void* d_out, int out_size, void* d_ws, size_t ws_size,
                              hipStream_t stream) {
    const float* hidden = (const float*)d_in[0];
    const float* W      = (const float*)d_in[1];
    const float* bias   = (const float*)d_in[2];
    float* out = (float*)d_out;

    ushort* Qb    = (ushort*)d_ws;                      //  8 MB  [bh][s][d]
    ushort* Ktd   = Qb + 4194304;                       //  8 MB  [bh][d][t]
    ushort* Vtd   = Ktd + 4194304;                      //  8 MB  [bh][d][t] (scan in place)
    float*  Mpart = (float*)(Vtd + 4194304);            //  2 MB  [4][bh][64][64]
    ushort* Abf   = (ushort*)(Mpart + 524288);          //  8 MB
    ushort* Wbf   = Abf + 4194304;                      //  6 MB
    // total ~40 MB of d_ws

    cast_both<<<(N8_A + N8_W + 255) / 256, 256, 0, stream>>>(hidden, W, Abf, Wbf);
    qkv_gemm_mfma<<<dim3(ROWS / 128, THREE_H / 128), 512, 0, stream>>>(Abf, Wbf, bias, Qb, Ktd, Vtd);
    vscan<<<512, 256, 0, stream>>>(Vtd);
    kvm_mfma<<<dim3(32, 4), 256, 0, stream>>>(Ktd, Vtd, Mpart);
    qm_mfma<<<dim3(32, 8), 256, 0, stream>>>(Qb, Mpart, out);
}

// Round 19
// 70.712 us; speedup vs baseline: 1.0766x; 1.0766x over previous
//
#include <hip/hip_runtime.h>

#define S 2048
#define B 2
#define H 1024
#define NH 16
#define HD 64
#define THREE_H 3072
#define ROWS (S*B)   // 4096

typedef __attribute__((ext_vector_type(8))) short short8;
typedef __attribute__((ext_vector_type(4))) float f32x4;
typedef const __attribute__((address_space(1))) unsigned int* gptr_t;
typedef __attribute__((address_space(3))) unsigned int* lptr_t;

#define N8_A (ROWS * H / 8)        // 524288
#define N8_W (THREE_H * H / 8)     // 393216

__device__ __forceinline__ ushort f2bf(float f) {
    union { float f; unsigned u; } v; v.f = f;
    unsigned r = v.u + 0x7fffu + ((v.u >> 16) & 1u);
    return (ushort)(r >> 16);
}
__device__ __forceinline__ float bf2f(ushort u) {
    union { unsigned u; float f; } v; v.u = ((unsigned)u) << 16;
    return v.f;
}

// ---------------------------------------------------------------------------
// Cast f32 -> bf16 for A and W in one launch (R12-proven)
// ---------------------------------------------------------------------------
__global__ void cast_both(const float* __restrict__ A, const float* __restrict__ W,
                          ushort* __restrict__ Ab, ushort* __restrict__ Wb) {
    int i = blockIdx.x * 256 + threadIdx.x;
    const float4* s4;
    ushort* dst;
    if (i < N8_A) { s4 = (const float4*)A; dst = Ab; }
    else if (i < N8_A + N8_W) { s4 = (const float4*)W; dst = Wb; i -= N8_A; }
    else return;
    float4 a = s4[2 * i], b = s4[2 * i + 1];
    short8 o;
    o[0] = f2bf(a.x); o[1] = f2bf(a.y); o[2] = f2bf(a.z); o[3] = f2bf(a.w);
    o[4] = f2bf(b.x); o[5] = f2bf(b.y); o[6] = f2bf(b.z); o[7] = f2bf(b.w);
    *(short8*)(dst + 8 * (size_t)i) = o;
}

// ---------------------------------------------------------------------------
// K1: bf16 MFMA GEMM — TRUE R12 config (best measured: GEMM <40.7 µs,
// total 71.0). 128x128 tile, EIGHT waves (4x2, 32x64 each), BK=32,
// SINGLE-buffered 16 KB LDS, STAGE -> sync -> compute -> sync.
// Conflict-free XOR swizzle (bits 1-2 of row; verified 0 conflicts in R12).
// Epilogue: Q -> [bh][s][d]; K,V -> [bh][d][t] packed-uint direct stores.
// ---------------------------------------------------------------------------
__global__ __launch_bounds__(512) void qkv_gemm_mfma(const ushort* __restrict__ Abf,
                                                     const ushort* __restrict__ Wbf,
                                                     const float* __restrict__ bias,
                                                     ushort* __restrict__ Qb,
                                                     ushort* __restrict__ Ktd,
                                                     ushort* __restrict__ Vtd) {
    __shared__ ushort Abuf[128 * 32];   // 8 KB
    __shared__ ushort Bbuf[128 * 32];   // 8 KB
    const int tid = threadIdx.x;
    const int wave = tid >> 6, lane = tid & 63;
    const int wr = wave >> 1, wc = wave & 1;     // 4x2 wave grid
    const int row0 = blockIdx.x * 128;
    const int col0 = blockIdx.y * 128;

    f32x4 acc[2][4] = {};

    const int lrow = lane >> 2;                             // 0..15 row in 16-row chunk
    const int gk = ((lane & 3) ^ ((lrow >> 1) & 3)) * 8;    // inverse-swizzled src octet
    const int il = lane & 15, ko = lane >> 4;

    for (int k0 = 0; k0 < H; k0 += 32) {
        {   // one 16-row chunk per wave per matrix
            int row = wave * 16 + lrow;
            __builtin_amdgcn_global_load_lds(
                (gptr_t)&Abf[(size_t)(row0 + row) * H + k0 + gk],
                (lptr_t)&Abuf[wave * 512 + lane * 8], 16, 0, 0);
            __builtin_amdgcn_global_load_lds(
                (gptr_t)&Wbf[(size_t)(col0 + row) * H + k0 + gk],
                (lptr_t)&Bbuf[wave * 512 + lane * 8], 16, 0, 0);
        }
        __syncthreads();

        short8 af[2], bfr[4];
#pragma unroll
        for (int m = 0; m < 2; ++m) {
            int ar = wr * 32 + m * 16 + il;
            af[m] = *(const short8*)&Abuf[ar * 32 + (ko ^ ((ar >> 1) & 3)) * 8];
        }
#pragma unroll
        for (int n = 0; n < 4; ++n) {
            int br = wc * 64 + n * 16 + il;
            bfr[n] = *(const short8*)&Bbuf[br * 32 + (ko ^ ((br >> 1) & 3)) * 8];
        }
#pragma unroll
        for (int m = 0; m < 2; ++m)
#pragma unroll
            for (int n = 0; n < 4; ++n)
                acc[m][n] = __builtin_amdgcn_mfma_f32_16x16x32_bf16(af[m], bfr[n], acc[m][n], 0, 0, 0);
        __syncthreads();
    }

    // ---- epilogue (R12-proven scatter; wave rows = wr*32 + m*16) ----
#pragma unroll
    for (int n = 0; n < 4; ++n) {
        int cbase = col0 + wc * 64 + n * 16;     // within one 64-col (h,sel) segment
        int h   = cbase / 192;
        int r3  = cbase % 192;
        int sel = r3 >> 6;                       // 0=q 1=k 2=v, wave-uniform
        int d   = (r3 & 63) + il;
        float bv = bias[cbase + il];
        if (sel == 0) {
#pragma unroll
            for (int m = 0; m < 2; ++m) {
                int rowb = row0 + wr * 32 + m * 16 + ko * 4;
#pragma unroll
                for (int j = 0; j < 4; ++j) {
                    int r = rowb + j;
                    int s = r >> 1, b = r & 1;   // r = s*B + b, B=2
                    Qb[((size_t)((b * NH + h) * S + s)) * HD + d] = f2bf(acc[m][n][j] + bv);
                }
            }
        } else {
            ushort* dst = (sel == 1) ? Ktd : Vtd;
            const size_t ro0 = ((size_t)(h)      * HD + d) * S;   // b=0 row
            const size_t ro1 = ((size_t)(NH + h) * HD + d) * S;   // b=1 row
#pragma unroll
            for (int m = 0; m < 2; ++m) {
                int t0 = (row0 + wr * 32 + m * 16 + ko * 4) >> 1;  // even
                uint lo = (uint)f2bf(acc[m][n][0] + bv) |
                          ((uint)f2bf(acc[m][n][2] + bv) << 16);   // t0,t0+1 (b=0)
                uint hi = (uint)f2bf(acc[m][n][1] + bv) |
                          ((uint)f2bf(acc[m][n][3] + bv) << 16);   // t0,t0+1 (b=1)
                *(uint*)&dst[ro0 + t0] = lo;
                *(uint*)&dst[ro1 + t0] = hi;
            }
        }
    }
}

// ---------------------------------------------------------------------------
// V suffix-scan, one wave per (bh,d) row of 2048 t, in place on Vtd. (R12)
// ---------------------------------------------------------------------------
__global__ __launch_bounds__(256) void vscan(ushort* __restrict__ Vtd) {
    const int row = blockIdx.x * 4 + (threadIdx.x >> 6);  // 0..2047 = bh*64+d
    const int lane = threadIdx.x & 63;
    ushort* vp = Vtd + (size_t)row * S + lane * 32;
    float v[32];
#pragma unroll
    for (int q = 0; q < 4; ++q) {
        short8 x = *(const short8*)(vp + q * 8);
#pragma unroll
        for (int k = 0; k < 8; ++k) v[q * 8 + k] = bf2f((ushort)x[k]);
    }
    float sum = 0.f;
#pragma unroll
    for (int k = 0; k < 32; ++k) sum += v[k];
    float t = sum;
#pragma unroll
    for (int off = 1; off < 64; off <<= 1) {
        float o = __shfl_down(t, off, 64);
        if (lane + off < 64) t += o;
    }
    float acc = t - sum;   // exclusive suffix (sum of lanes > lane)
#pragma unroll
    for (int k = 31; k >= 0; --k) { acc += v[k]; v[k] = acc; }
#pragma unroll
    for (int q = 0; q < 4; ++q) {
        short8 o;
#pragma unroll
        for (int k = 0; k < 8; ++k) o[k] = f2bf(v[q * 8 + k]);
        *(short8*)(vp + q * 8) = o;
    }
}

// ---------------------------------------------------------------------------
// K3: M[i][j] = sum_t Ktd[i][t]*Vtd[j][t] via MFMA; cross-wave LDS reduce
// -> Mpart has 4 slices. (R12-proven)
// ---------------------------------------------------------------------------
__global__ __launch_bounds__(256) void kvm_mfma(const ushort* __restrict__ Kt,
                                                const ushort* __restrict__ Vt,
                                                float* __restrict__ Mpart) {
    __shared__ float red[2][4096];   // 32 KB
    const int bh = blockIdx.x, kb = blockIdx.y;
    const int tid = threadIdx.x, wave = tid >> 6, lane = tid & 63;
    const int slice = kb * 4 + wave;
    const ushort* Kp = Kt + (size_t)bh * HD * S;
    const ushort* Vp = Vt + (size_t)bh * HD * S;
    f32x4 acc[4][4] = {};
    const int il = lane & 15, g = lane >> 4;
    const int tbase = slice * 128 + g * 8;
#pragma unroll
    for (int ks = 0; ks < 4; ++ks) {
        const int t = tbase + ks * 32;
        short8 af[4], bfv[4];
#pragma unroll
        for (int m = 0; m < 4; ++m) af[m]  = *(const short8*)&Kp[(size_t)(m * 16 + il) * S + t];
#pragma unroll
        for (int n = 0; n < 4; ++n) bfv[n] = *(const short8*)&Vp[(size_t)(n * 16 + il) * S + t];
#pragma unroll
        for (int m = 0; m < 4; ++m)
#pragma unroll
            for (int n = 0; n < 4; ++n)
                acc[m][n] = __builtin_amdgcn_mfma_f32_16x16x32_bf16(af[m], bfv[n], acc[m][n], 0, 0, 0);
    }
#define DUMP(dstbuf)                                                        \
    { float* _d = (dstbuf);                                                 \
      _Pragma("unroll") for (int m = 0; m < 4; ++m)                         \
      _Pragma("unroll") for (int n = 0; n < 4; ++n)                         \
      _Pragma("unroll") for (int j = 0; j < 4; ++j)                         \
          _d[(m * 16 + g * 4 + j) * 64 + n * 16 + il] = acc[m][n][j]; }
#define ADDIN(srcbuf)                                                       \
    { const float* _s = (srcbuf);                                           \
      _Pragma("unroll") for (int m = 0; m < 4; ++m)                         \
      _Pragma("unroll") for (int n = 0; n < 4; ++n)                         \
      _Pragma("unroll") for (int j = 0; j < 4; ++j)                         \
          acc[m][n][j] += _s[(m * 16 + g * 4 + j) * 64 + n * 16 + il]; }
    if (wave == 1) DUMP(red[0]);
    if (wave == 3) DUMP(red[1]);
    __syncthreads();
    if (wave == 0) ADDIN(red[0]);
    if (wave == 2) ADDIN(red[1]);
    __syncthreads();
    if (wave == 2) DUMP(red[0]);
    __syncthreads();
    if (wave == 0) {
        ADDIN(red[0]);
        float* Mp = Mpart + ((size_t)kb * 32 + bh) * 4096;
#pragma unroll
        for (int m = 0; m < 4; ++m)
#pragma unroll
            for (int n = 0; n < 4; ++n)
#pragma unroll
                for (int j = 0; j < 4; ++j)
                    Mp[(m * 16 + g * 4 + j) * 64 + n * 16 + il] = acc[m][n][j];
    }
#undef DUMP
#undef ADDIN
}

// ---------------------------------------------------------------------------
// K4: out = scale * Q·M via MFMA; folds the 4-slice Mpart reduce. (R12)
// ---------------------------------------------------------------------------
__global__ __launch_bounds__(256) void qm_mfma(const ushort* __restrict__ Qb,
                                               const float* __restrict__ Mpart,
                                               float* __restrict__ out) {
    __shared__ ushort Mt[64][72];   // Mt[d][i] = M[i][d], bf16
    const int bh = blockIdx.x, b = bh >> 4, h = bh & 15;
    const int tid = threadIdx.x;
    {
        const int i = tid >> 2, jq = (tid & 3) * 16;
        f32x4 s0 = {}, s1 = {}, s2 = {}, s3 = {};
#pragma unroll
        for (int sl = 0; sl < 4; ++sl) {
            const float* p = Mpart + ((size_t)sl * 32 + bh) * 4096 + i * 64 + jq;
            s0 += *(const f32x4*)(p);
            s1 += *(const f32x4*)(p + 4);
            s2 += *(const f32x4*)(p + 8);
            s3 += *(const f32x4*)(p + 12);
        }
#pragma unroll
        for (int k = 0; k < 4; ++k) {
            Mt[jq + 0  + k][i] = f2bf(s0[k]);
            Mt[jq + 4  + k][i] = f2bf(s1[k]);
            Mt[jq + 8  + k][i] = f2bf(s2[k]);
            Mt[jq + 12 + k][i] = f2bf(s3[k]);
        }
    }
    __syncthreads();
    const int wave = tid >> 6, lane = tid & 63;
    const int sl15 = lane & 15, koct = (lane >> 4) * 8;
    const int s0b = blockIdx.y * 256 + wave * 64;
    f32x4 acc[4][4] = {};
#pragma unroll
    for (int ks = 0; ks < 2; ++ks) {
        short8 af[4], bfv[4];
#pragma unroll
        for (int m = 0; m < 4; ++m) {
            int s = s0b + m * 16 + sl15;
            af[m] = *(const short8*)&Qb[((size_t)bh * S + s) * HD + ks * 32 + koct];
        }
#pragma unroll
        for (int n = 0; n < 4; ++n)
            bfv[n] = *(const short8*)&Mt[n * 16 + sl15][ks * 32 + koct];
#pragma unroll
        for (int m = 0; m < 4; ++m)
#pragma unroll
            for (int n = 0; n < 4; ++n)
                acc[m][n] = __builtin_amdgcn_mfma_f32_16x16x32_bf16(af[m], bfv[n], acc[m][n], 0, 0, 0);
    }
    const float scale = 0.125f * 0.02209708691207961f;  // HD^-0.5 * S^-0.5
#pragma unroll
    for (int m = 0; m < 4; ++m)
#pragma unroll
        for (int n = 0; n < 4; ++n)
#pragma unroll
            for (int j = 0; j < 4; ++j) {
                int s = s0b + m * 16 + (lane >> 4) * 4 + j;
                int d = n * 16 + sl15;
                out[(size_t)(s * B + b) * H + h * 64 + d] = acc[m][n][j] * scale;
            }
}

// ---------------------------------------------------------------------------
extern "C" void kernel_launch(void* const* d_in, const int* in_sizes, int n_in,
                              void* d_out, int out_size, void* d_ws, size_t ws_size,
                              hipStream_t stream) {
    const float* hidden = (const float*)d_in[0];
    const float* W      = (const float*)d_in[1];
    const float* bias   = (const float*)d_in[2];
    float* out = (float*)d_out;

    ushort* Qb    = (ushort*)d_ws;                      //  8 MB  [bh][s][d]
    ushort* Ktd   = Qb + 4194304;                       //  8 MB  [bh][d][t]
    ushort* Vtd   = Ktd + 4194304;                      //  8 MB  [bh][d][t] (scan in place)
    float*  Mpart = (float*)(Vtd + 4194304);            //  2 MB  [4][bh][64][64]
    ushort* Abf   = (ushort*)(Mpart + 524288);          //  8 MB
    ushort* Wbf   = Abf + 4194304;                      //  6 MB
    // total ~40 MB of d_ws

    cast_both<<<(N8_A + N8_W + 255) / 256, 256, 0, stream>>>(hidden, W, Abf, Wbf);
    qkv_gemm_mfma<<<dim3(ROWS / 128, THREE_H / 128), 512, 0, stream>>>(Abf, Wbf, bias, Qb, Ktd, Vtd);
    vscan<<<512, 256, 0, stream>>>(Vtd);
    kvm_mfma<<<dim3(32, 4), 256, 0, stream>>>(Ktd, Vtd, Mpart);
    qm_mfma<<<dim3(32, 8), 256, 0, stream>>>(Qb, Mpart, out);
}